// Round 1
// 262.653 us; speedup vs baseline: 1.3997x; 1.3997x over previous
//
#include <hip/hip_runtime.h>

typedef _Float16 f16;
typedef _Float16 f16x8 __attribute__((ext_vector_type(8)));
typedef float    f32x4 __attribute__((ext_vector_type(4)));
typedef unsigned int u32x2 __attribute__((ext_vector_type(2)));

#define B_ 4
#define C_ 512
#define N_ 4096
#define M_ 64

__device__ __forceinline__ unsigned pk2(float a, float b) {
    union { f16 h[2]; unsigned u; } t;
    t.h[0] = (f16)a; t.h[1] = (f16)b;
    return t.u;
}

// ---------------------------------------------------------------------------
// Kernel T: x [B][C][N] fp32 -> xtf in qkv B-FRAGMENT ORDER (unchanged).
// ---------------------------------------------------------------------------
__global__ __launch_bounds__(256) void transpose_cast(
    const float* __restrict__ x, f16* __restrict__ xtf)
{
    __shared__ float sT[64][65];
    const int n0 = blockIdx.x * 64;
    const int c0 = blockIdx.y * 64;
    const int b  = blockIdx.z;
    const int tid = threadIdx.x;

    #pragma unroll
    for (int i = 0; i < 4; ++i) {
        int e = i * 256 + tid;
        int c = e >> 4;              // 0..63
        int n4 = (e & 15) * 4;       // 0..60, lanes consecutive -> coalesced 16B
        float4 v = *(const float4*)(x + ((size_t)(b * C_ + c0 + c)) * N_ + n0 + n4);
        sT[c][n4 + 0] = v.x; sT[c][n4 + 1] = v.y;
        sT[c][n4 + 2] = v.z; sT[c][n4 + 3] = v.w;
    }
    __syncthreads();

    const int w = tid >> 6, lane = tid & 63, l15 = lane & 15, quad = lane >> 4;
    #pragma unroll
    for (int j = 0; j < 2; ++j) {
        const int fb  = w * 2 + j;        // 0..7: (lnt 0..3) x (lck 0..1)
        const int lnt = fb >> 1, lck = fb & 1;
        const int nl  = lnt * 16 + l15;
        const int cb  = lck * 32 + quad * 8;
        f16x8 o;
        #pragma unroll
        for (int jj = 0; jj < 8; ++jj) o[jj] = (f16)sT[cb + jj][nl];
        const int ntg = (n0 >> 4) + lnt;
        const int ck  = (c0 >> 5) + lck;
        size_t idx = (((size_t)(b * 256 + ntg)) * 16 + ck) * 512 + lane * 8;
        *(f16x8*)(xtf + idx) = o;
    }
}

// ---------------------------------------------------------------------------
// Kernel A: fused qkv GEMM (unchanged, validated).
// ---------------------------------------------------------------------------
__global__ __launch_bounds__(512) void qkv_gemm(
    const f16* __restrict__ xtf,
    const float* __restrict__ Wq, const float* __restrict__ bq,
    const float* __restrict__ Wk, const float* __restrict__ bk,
    const float* __restrict__ Wv, const float* __restrict__ bv,
    f16* __restrict__ qt, f16* __restrict__ ktf, f16* __restrict__ vf)
{
    const int tid  = threadIdx.x;
    const int w    = tid >> 6;
    const int lane = tid & 63;
    const int l15  = lane & 15;
    const int quad = lane >> 4;
    const int nBase = blockIdx.x * 128;
    const int oseg  = blockIdx.y;
    const int b     = blockIdx.z;
    const int ot16  = w & 3;
    const int nhalf = w >> 2;

    const float* Wsel;
    if (oseg == 0)      Wsel = Wq;
    else if (oseg == 1) Wsel = Wk;
    else                Wsel = Wv + (size_t)(oseg - 2) * 64 * C_;

    const int orow = ot16 * 16 + l15;
    const float* wp = Wsel + (size_t)orow * C_ + quad * 8;

    const f16* xfb[4];
    #pragma unroll
    for (int ns = 0; ns < 4; ++ns) {
        int ntg = (nBase >> 4) + nhalf * 4 + ns;
        xfb[ns] = xtf + (((size_t)(b * 256 + ntg)) * 16) * 512 + lane * 8;
    }

    f32x4 acc[4] = {};

    float4 w0c = *(const float4*)(wp);
    float4 w1c = *(const float4*)(wp + 4);
    f16x8 b8c[4];
    #pragma unroll
    for (int ns = 0; ns < 4; ++ns) b8c[ns] = *(const f16x8*)(xfb[ns]);

    for (int ck = 0; ck < 16; ++ck) {
        float4 w0n, w1n;
        f16x8  b8n[4];
        if (ck + 1 < 16) {
            w0n = *(const float4*)(wp + ck * 32 + 32);
            w1n = *(const float4*)(wp + ck * 32 + 36);
            #pragma unroll
            for (int ns = 0; ns < 4; ++ns)
                b8n[ns] = *(const f16x8*)(xfb[ns] + (ck + 1) * 512);
        }
        f16x8 a8;
        a8[0]=(f16)w0c.x; a8[1]=(f16)w0c.y; a8[2]=(f16)w0c.z; a8[3]=(f16)w0c.w;
        a8[4]=(f16)w1c.x; a8[5]=(f16)w1c.y; a8[6]=(f16)w1c.z; a8[7]=(f16)w1c.w;
        #pragma unroll
        for (int ns = 0; ns < 4; ++ns)
            acc[ns] = __builtin_amdgcn_mfma_f32_16x16x32_f16(a8, b8c[ns], acc[ns], 0, 0, 0);
        w0c = w0n; w1c = w1n;
        #pragma unroll
        for (int ns = 0; ns < 4; ++ns) b8c[ns] = b8n[ns];
    }

    #pragma unroll
    for (int ns = 0; ns < 4; ++ns) {
        int n = nBase + nhalf * 64 + ns * 16 + l15;
        #pragma unroll
        for (int r = 0; r < 4; ++r) {
            int olocal = ot16 * 16 + quad * 4 + r;
            float bias;
            if (oseg == 0)      bias = bq[olocal];
            else if (oseg == 1) bias = bk[olocal];
            else                bias = bv[(oseg - 2) * 64 + olocal];
            f16 h = (f16)(acc[ns][r] + bias);
            if (oseg == 0) {
                qt[((size_t)(b * N_ + n)) * M_ + olocal] = h;
            } else if (oseg == 1) {
                size_t idx = (((size_t)b * 256 + (n >> 4)) * 2 + (olocal >> 5)) * 512
                           + (size_t)((((olocal >> 3) & 3) * 16 + (n & 15)) * 8) + (olocal & 7);
                ktf[idx] = h;
            } else {
                int c = (oseg - 2) * 64 + olocal;
                size_t idx = ((size_t)b * (C_ * N_)) + (size_t)(c >> 4) * 65536
                           + (size_t)(n >> 6) * 1024 + (size_t)((n >> 5) & 1) * 512
                           + (size_t)((((n >> 3) & 3) * 16 + (c & 15)) * 8) + (n & 7);
                vf[idx] = h;
            }
        }
    }
}

// ---------------------------------------------------------------------------
// Kernel B (REWRITTEN): deduplicated fused attention.
//  - 512 threads / 8 waves, 64 i-rows per block, grid 256 (1 block/CU,
//    XCD x serves batch (x&7)>>1 so V[b] stays in that XCD's L2).
//  - Pass 1: exact rowmax; wave w covers j in [w*512, w*512+512) only
//    (no duplication), partials combined via 2KB LDS.
//  - Pass 2: wave w owns QK sub-tile jt=w&3 for is-pair w>>2 (4 MFMA/tile,
//    exp computed ONCE per P element), P written packed-f16 to an
//    XOR-swizzled (byte ^= (i&7)<<4) double-buffered LDS tile; after one
//    barrier/tile each wave ds_read_b128s its PV B-fragments (replaces the
//    former 32 ds_bpermute/tile). PV split by channel: wave owns 64 c,
//    so V is loaded exactly once per block (2GB -> 1GB L2 traffic).
//  Executed MFMA FLOPs: 137.4 GF -> 85.9 GF.
// ---------------------------------------------------------------------------
__global__ __launch_bounds__(512, 2) void attn(
    const f16* __restrict__ qt, const f16* __restrict__ ktf,
    const f16* __restrict__ vf, const float* __restrict__ x,
    const float* __restrict__ gamma, float* __restrict__ out)
{
    __shared__ __align__(16) char Pb[2][8192];   // P: 64 i x 64 j f16, dbuf
    __shared__ float mxs[8][4][16];
    __shared__ float lss[8][4][16];

    const int tid  = threadIdx.x;
    const int w    = tid >> 6;                  // 0..7
    const int lane = tid & 63;
    const int l15  = lane & 15;
    const int quad = lane >> 4;
    const int jt   = w & 3;                     // owned QK j-subtile (pass 2)
    const int ish  = w >> 2;                    // owned is-pair {2ish, 2ish+1}
    const int is0  = ish * 2, is1 = is0 + 1;

    const int lin  = blockIdx.x;                // 0..255
    const int b    = (lin & 7) >> 1;            // XCD-pinned batch
    const int iblk = ((lin >> 3) << 1) | (lin & 1);  // 0..63
    const int i0   = iblk * 64;

    const f16* kln = ktf + (size_t)b * (N_ * M_) + lane * 8;
    const f16* vln = vf  + (size_t)b * (C_ * N_) + lane * 8;

    // Q fragments, all 4 is tiles (pass 1 needs all four)
    f16x8 bqf[4][2];
    #pragma unroll
    for (int is = 0; is < 4; ++is)
        #pragma unroll
        for (int kh = 0; kh < 2; ++kh)
            bqf[is][kh] = *(const f16x8*)(qt + ((size_t)(b * N_ + i0 + is * 16 + l15)) * M_
                                          + kh * 32 + quad * 8);

    // ---------------- pass 1: rowmax, j-range split across waves ----------
    float mx[4];
    #pragma unroll
    for (int is = 0; is < 4; ++is) mx[is] = -3.0e38f;
    {
        const f16* kw = kln + (size_t)(w * 512) * 64;
        f16x8 akc[4][2];
        #pragma unroll
        for (int t = 0; t < 4; ++t)
            #pragma unroll
            for (int kh = 0; kh < 2; ++kh)
                akc[t][kh] = *(const f16x8*)(kw + t * 1024 + kh * 512);

        #pragma unroll 2
        for (int jj = 0; jj < 512; jj += 64) {
            f16x8 akn[4][2];
            if (jj + 64 < 512) {
                const f16* kn = kw + (size_t)(jj + 64) * 64;
                #pragma unroll
                for (int t = 0; t < 4; ++t)
                    #pragma unroll
                    for (int kh = 0; kh < 2; ++kh)
                        akn[t][kh] = *(const f16x8*)(kn + t * 1024 + kh * 512);
            }
            #pragma unroll
            for (int t = 0; t < 4; ++t) {
                #pragma unroll
                for (int is = 0; is < 4; ++is) {
                    f32x4 s = {};
                    s = __builtin_amdgcn_mfma_f32_16x16x32_f16(akc[t][0], bqf[is][0], s, 0, 0, 0);
                    s = __builtin_amdgcn_mfma_f32_16x16x32_f16(akc[t][1], bqf[is][1], s, 0, 0, 0);
                    mx[is] = fmaxf(mx[is], fmaxf(fmaxf(s[0], s[1]), fmaxf(s[2], s[3])));
                }
            }
            #pragma unroll
            for (int t = 0; t < 4; ++t)
                #pragma unroll
                for (int kh = 0; kh < 2; ++kh)
                    akc[t][kh] = akn[t][kh];
        }
    }
    #pragma unroll
    for (int is = 0; is < 4; ++is) {
        mx[is] = fmaxf(mx[is], __shfl_xor(mx[is], 16, 64));
        mx[is] = fmaxf(mx[is], __shfl_xor(mx[is], 32, 64));
    }
    if (lane < 16) {
        #pragma unroll
        for (int is = 0; is < 4; ++is) mxs[w][is][lane] = mx[is];
    }
    __syncthreads();
    float m0 = -3.0e38f, m1 = -3.0e38f;
    #pragma unroll
    for (int w2 = 0; w2 < 8; ++w2) {
        m0 = fmaxf(m0, mxs[w2][is0][l15]);
        m1 = fmaxf(m1, mxs[w2][is1][l15]);
    }

    // ---------------- pass 2: P (owned jt) -> LDS -> PV --------------------
    f32x4 acc[4][4] = {};                       // [ct][is]
    float lp0 = 0.f, lp1 = 0.f;

    char* pbB = (char*)&Pb[0][0];
    const int swz = (l15 & 7) << 4;
    const int wb0 = ((is0 * 16 + l15) * 128 + (jt * 16 + quad * 4) * 2) ^ swz;
    const int wb1 = wb0 + 2048;                 // is1 row (+16*128); swz < 128
    int rb[4][2];
    #pragma unroll
    for (int is = 0; is < 4; ++is)
        #pragma unroll
        for (int kh = 0; kh < 2; ++kh)
            rb[is][kh] = ((is * 16 + l15) * 128 + kh * 64 + quad * 16) ^ swz;

    const f16* kp = kln + (size_t)(jt * 16) * 64;
    f16x8 ak0 = *(const f16x8*)(kp);
    f16x8 ak1 = *(const f16x8*)(kp + 512);
    const int cw = w * 4;                       // owned c16-group base
    int buf = 0;

    for (int j0 = 0; j0 < N_; j0 += 64) {
        const f16* vt = vln + (size_t)(j0 >> 6) * 1024;
        f16x8 vb0[4];
        #pragma unroll
        for (int ct = 0; ct < 4; ++ct)
            vb0[ct] = *(const f16x8*)(vt + (size_t)(cw + ct) * 65536);

        f32x4 s0 = {}, s1 = {};
        s0 = __builtin_amdgcn_mfma_f32_16x16x32_f16(ak0, bqf[is0][0], s0, 0, 0, 0);
        s0 = __builtin_amdgcn_mfma_f32_16x16x32_f16(ak1, bqf[is0][1], s0, 0, 0, 0);
        s1 = __builtin_amdgcn_mfma_f32_16x16x32_f16(ak0, bqf[is1][0], s1, 0, 0, 0);
        s1 = __builtin_amdgcn_mfma_f32_16x16x32_f16(ak1, bqf[is1][1], s1, 0, 0, 0);

        f16x8 akn0 = ak0, akn1 = ak1;
        if (j0 + 64 < N_) {
            const f16* kn = kp + (size_t)(j0 + 64) * 64;
            akn0 = *(const f16x8*)(kn);
            akn1 = *(const f16x8*)(kn + 512);
        }

        {
            float p0 = __expf(s0[0] - m0), p1 = __expf(s0[1] - m0);
            float p2 = __expf(s0[2] - m0), p3 = __expf(s0[3] - m0);
            lp0 += (p0 + p1) + (p2 + p3);
            u32x2 pw = { pk2(p0, p1), pk2(p2, p3) };
            *(u32x2*)(pbB + buf * 8192 + wb0) = pw;
        }
        {
            float q0 = __expf(s1[0] - m1), q1 = __expf(s1[1] - m1);
            float q2 = __expf(s1[2] - m1), q3 = __expf(s1[3] - m1);
            lp1 += (q0 + q1) + (q2 + q3);
            u32x2 pw = { pk2(q0, q1), pk2(q2, q3) };
            *(u32x2*)(pbB + buf * 8192 + wb1) = pw;
        }

        f16x8 vb1[4];
        #pragma unroll
        for (int ct = 0; ct < 4; ++ct)
            vb1[ct] = *(const f16x8*)(vt + (size_t)(cw + ct) * 65536 + 512);

        __syncthreads();   // P[buf] complete; also fences prev-tile readers

        f16x8 pbf[4][2];
        #pragma unroll
        for (int is = 0; is < 4; ++is)
            #pragma unroll
            for (int kh = 0; kh < 2; ++kh)
                pbf[is][kh] = *(const f16x8*)(pbB + buf * 8192 + rb[is][kh]);

        __builtin_amdgcn_s_setprio(1);
        #pragma unroll
        for (int ct = 0; ct < 4; ++ct)
            #pragma unroll
            for (int is = 0; is < 4; ++is)
                acc[ct][is] = __builtin_amdgcn_mfma_f32_16x16x32_f16(vb0[ct], pbf[is][0], acc[ct][is], 0, 0, 0);
        #pragma unroll
        for (int ct = 0; ct < 4; ++ct)
            #pragma unroll
            for (int is = 0; is < 4; ++is)
                acc[ct][is] = __builtin_amdgcn_mfma_f32_16x16x32_f16(vb1[ct], pbf[is][1], acc[ct][is], 0, 0, 0);
        __builtin_amdgcn_s_setprio(0);

        ak0 = akn0; ak1 = akn1;
        buf ^= 1;
    }

    // ---------------- l combine + epilogue ---------------------------------
    lp0 += __shfl_xor(lp0, 16, 64);
    lp0 += __shfl_xor(lp0, 32, 64);
    lp1 += __shfl_xor(lp1, 16, 64);
    lp1 += __shfl_xor(lp1, 32, 64);
    if (lane < 16) { lss[w][is0][lane] = lp0; lss[w][is1][lane] = lp1; }
    __syncthreads();

    float linv[4];
    #pragma unroll
    for (int is = 0; is < 4; ++is) {
        const int wb = (is >> 1) * 4;
        float l = (lss[wb + 0][is][l15] + lss[wb + 1][is][l15])
                + (lss[wb + 2][is][l15] + lss[wb + 3][is][l15]);
        linv[is] = 1.0f / l;
    }

    const float g = gamma[0];
    #pragma unroll
    for (int is = 0; is < 4; ++is) {
        const int i = i0 + is * 16 + l15;
        #pragma unroll
        for (int ct = 0; ct < 4; ++ct) {
            #pragma unroll
            for (int r = 0; r < 4; ++r) {
                const int c = w * 64 + ct * 16 + quad * 4 + r;
                const size_t idx = ((size_t)(b * C_ + c)) * N_ + i;
                out[idx] = g * (acc[ct][is][r] * linv[is]) + x[idx];
            }
        }
    }
}

// ---------------------------------------------------------------------------
extern "C" void kernel_launch(void* const* d_in, const int* in_sizes, int n_in,
                              void* d_out, int out_size, void* d_ws, size_t ws_size,
                              hipStream_t stream)
{
    const float* x     = (const float*)d_in[0];
    const float* Wq    = (const float*)d_in[1];
    const float* bq    = (const float*)d_in[2];
    const float* Wk    = (const float*)d_in[3];
    const float* bk    = (const float*)d_in[4];
    const float* Wv    = (const float*)d_in[5];
    const float* bv    = (const float*)d_in[6];
    const float* gamma = (const float*)d_in[7];
    float* out = (float*)d_out;

    char* ws = (char*)d_ws;
    f16* xtf = (f16*)ws;                                   // B*N*C   (16 MB)
    f16* qt  = (f16*)(ws + (size_t)B_ * N_ * C_ * 2);      // B*N*M   ( 2 MB)
    f16* ktf = qt + (size_t)B_ * N_ * M_;                  // B*N*M   ( 2 MB)
    f16* vf  = ktf + (size_t)B_ * N_ * M_;                 // B*C*N   (16 MB)

    transpose_cast<<<dim3(N_ / 64, C_ / 64, B_), 256, 0, stream>>>(x, xtf);
    qkv_gemm<<<dim3(N_ / 128, 10, B_), 512, 0, stream>>>(
        xtf, Wq, bq, Wk, bk, Wv, bv, qt, ktf, vf);
    attn<<<dim3(256), 512, 0, stream>>>(qt, ktf, vf, x, gamma, out);
}

// Round 2
// 259.206 us; speedup vs baseline: 1.4183x; 1.0133x over previous
//
#include <hip/hip_runtime.h>

typedef _Float16 f16;
typedef _Float16 f16x8 __attribute__((ext_vector_type(8)));
typedef float    f32x4 __attribute__((ext_vector_type(4)));
typedef unsigned int u32x2 __attribute__((ext_vector_type(2)));

#define B_ 4
#define C_ 512
#define N_ 4096
#define M_ 64

__device__ __forceinline__ unsigned pk2(float a, float b) {
    union { f16 h[2]; unsigned u; } t;
    t.h[0] = (f16)a; t.h[1] = (f16)b;
    return t.u;
}

// ---------------------------------------------------------------------------
// Kernel T: x [B][C][N] fp32 -> xtf in qkv B-FRAGMENT ORDER (unchanged).
// ---------------------------------------------------------------------------
__global__ __launch_bounds__(256) void transpose_cast(
    const float* __restrict__ x, f16* __restrict__ xtf)
{
    __shared__ float sT[64][65];
    const int n0 = blockIdx.x * 64;
    const int c0 = blockIdx.y * 64;
    const int b  = blockIdx.z;
    const int tid = threadIdx.x;

    #pragma unroll
    for (int i = 0; i < 4; ++i) {
        int e = i * 256 + tid;
        int c = e >> 4;              // 0..63
        int n4 = (e & 15) * 4;       // 0..60, lanes consecutive -> coalesced 16B
        float4 v = *(const float4*)(x + ((size_t)(b * C_ + c0 + c)) * N_ + n0 + n4);
        sT[c][n4 + 0] = v.x; sT[c][n4 + 1] = v.y;
        sT[c][n4 + 2] = v.z; sT[c][n4 + 3] = v.w;
    }
    __syncthreads();

    const int w = tid >> 6, lane = tid & 63, l15 = lane & 15, quad = lane >> 4;
    #pragma unroll
    for (int j = 0; j < 2; ++j) {
        const int fb  = w * 2 + j;        // 0..7: (lnt 0..3) x (lck 0..1)
        const int lnt = fb >> 1, lck = fb & 1;
        const int nl  = lnt * 16 + l15;
        const int cb  = lck * 32 + quad * 8;
        f16x8 o;
        #pragma unroll
        for (int jj = 0; jj < 8; ++jj) o[jj] = (f16)sT[cb + jj][nl];
        const int ntg = (n0 >> 4) + lnt;
        const int ck  = (c0 >> 5) + lck;
        size_t idx = (((size_t)(b * 256 + ntg)) * 16 + ck) * 512 + lane * 8;
        *(f16x8*)(xtf + idx) = o;
    }
}

// ---------------------------------------------------------------------------
// Kernel A: fused qkv GEMM (unchanged, validated).
// ---------------------------------------------------------------------------
__global__ __launch_bounds__(512) void qkv_gemm(
    const f16* __restrict__ xtf,
    const float* __restrict__ Wq, const float* __restrict__ bq,
    const float* __restrict__ Wk, const float* __restrict__ bk,
    const float* __restrict__ Wv, const float* __restrict__ bv,
    f16* __restrict__ qt, f16* __restrict__ ktf, f16* __restrict__ vf)
{
    const int tid  = threadIdx.x;
    const int w    = tid >> 6;
    const int lane = tid & 63;
    const int l15  = lane & 15;
    const int quad = lane >> 4;
    const int nBase = blockIdx.x * 128;
    const int oseg  = blockIdx.y;
    const int b     = blockIdx.z;
    const int ot16  = w & 3;
    const int nhalf = w >> 2;

    const float* Wsel;
    if (oseg == 0)      Wsel = Wq;
    else if (oseg == 1) Wsel = Wk;
    else                Wsel = Wv + (size_t)(oseg - 2) * 64 * C_;

    const int orow = ot16 * 16 + l15;
    const float* wp = Wsel + (size_t)orow * C_ + quad * 8;

    const f16* xfb[4];
    #pragma unroll
    for (int ns = 0; ns < 4; ++ns) {
        int ntg = (nBase >> 4) + nhalf * 4 + ns;
        xfb[ns] = xtf + (((size_t)(b * 256 + ntg)) * 16) * 512 + lane * 8;
    }

    f32x4 acc[4] = {};

    float4 w0c = *(const float4*)(wp);
    float4 w1c = *(const float4*)(wp + 4);
    f16x8 b8c[4];
    #pragma unroll
    for (int ns = 0; ns < 4; ++ns) b8c[ns] = *(const f16x8*)(xfb[ns]);

    for (int ck = 0; ck < 16; ++ck) {
        float4 w0n, w1n;
        f16x8  b8n[4];
        if (ck + 1 < 16) {
            w0n = *(const float4*)(wp + ck * 32 + 32);
            w1n = *(const float4*)(wp + ck * 32 + 36);
            #pragma unroll
            for (int ns = 0; ns < 4; ++ns)
                b8n[ns] = *(const f16x8*)(xfb[ns] + (ck + 1) * 512);
        }
        f16x8 a8;
        a8[0]=(f16)w0c.x; a8[1]=(f16)w0c.y; a8[2]=(f16)w0c.z; a8[3]=(f16)w0c.w;
        a8[4]=(f16)w1c.x; a8[5]=(f16)w1c.y; a8[6]=(f16)w1c.z; a8[7]=(f16)w1c.w;
        #pragma unroll
        for (int ns = 0; ns < 4; ++ns)
            acc[ns] = __builtin_amdgcn_mfma_f32_16x16x32_f16(a8, b8c[ns], acc[ns], 0, 0, 0);
        w0c = w0n; w1c = w1n;
        #pragma unroll
        for (int ns = 0; ns < 4; ++ns) b8c[ns] = b8n[ns];
    }

    #pragma unroll
    for (int ns = 0; ns < 4; ++ns) {
        int n = nBase + nhalf * 64 + ns * 16 + l15;
        #pragma unroll
        for (int r = 0; r < 4; ++r) {
            int olocal = ot16 * 16 + quad * 4 + r;
            float bias;
            if (oseg == 0)      bias = bq[olocal];
            else if (oseg == 1) bias = bk[olocal];
            else                bias = bv[(oseg - 2) * 64 + olocal];
            f16 h = (f16)(acc[ns][r] + bias);
            if (oseg == 0) {
                qt[((size_t)(b * N_ + n)) * M_ + olocal] = h;
            } else if (oseg == 1) {
                size_t idx = (((size_t)b * 256 + (n >> 4)) * 2 + (olocal >> 5)) * 512
                           + (size_t)((((olocal >> 3) & 3) * 16 + (n & 15)) * 8) + (olocal & 7);
                ktf[idx] = h;
            } else {
                int c = (oseg - 2) * 64 + olocal;
                size_t idx = ((size_t)b * (C_ * N_)) + (size_t)(c >> 4) * 65536
                           + (size_t)(n >> 6) * 1024 + (size_t)((n >> 5) & 1) * 512
                           + (size_t)((((n >> 3) & 3) * 16 + (c & 15)) * 8) + (n & 7);
                vf[idx] = h;
            }
        }
    }
}

// ---------------------------------------------------------------------------
// Kernel B: deduplicated fused attention, SOFTWARE-PIPELINED pass 2.
//  Interval t: {ds_read P(t) | QK(t+1) | prefetch K(t+2),V(t+1) |
//               exp->write P(t+1) | PV(t)} -> barrier.
//  P consumed at interval t was produced before the PREVIOUS barrier, so PV
//  never waits on this interval's QK/exp chain; MFMA pipe gets QK+PV
//  back-to-back while exp runs on the VALU pipe.
//  Grid stays 256 (1 block/CU): V re-read is 4MB/block -> 1GB L2 total
//  (~29us at 34.5TB/s); more blocks/CU would multiply this.
//  Extra VGPR for V/K register prefetch is free (occupancy >8 waves/CU
//  useless at 1 block/CU).
// ---------------------------------------------------------------------------
__global__ __launch_bounds__(512, 2) void attn(
    const f16* __restrict__ qt, const f16* __restrict__ ktf,
    const f16* __restrict__ vf, const float* __restrict__ x,
    const float* __restrict__ gamma, float* __restrict__ out)
{
    __shared__ __align__(16) char Pb[2][8192];   // P: 64 i x 64 j f16, dbuf
    __shared__ float mxs[8][4][16];
    __shared__ float lss[8][4][16];

    const int tid  = threadIdx.x;
    const int w    = tid >> 6;                  // 0..7
    const int lane = tid & 63;
    const int l15  = lane & 15;
    const int quad = lane >> 4;
    const int jt   = w & 3;                     // owned QK j-subtile (pass 2)
    const int ish  = w >> 2;                    // owned is-pair {2ish, 2ish+1}
    const int is0  = ish * 2, is1 = is0 + 1;

    const int lin  = blockIdx.x;                // 0..255
    const int b    = (lin & 7) >> 1;            // XCD-pinned batch
    const int iblk = ((lin >> 3) << 1) | (lin & 1);  // 0..63
    const int i0   = iblk * 64;

    const f16* kln = ktf + (size_t)b * (N_ * M_) + lane * 8;
    const f16* vln = vf  + (size_t)b * (C_ * N_) + lane * 8;

    // Q fragments, all 4 is tiles (pass 1 needs all four)
    f16x8 bqf[4][2];
    #pragma unroll
    for (int is = 0; is < 4; ++is)
        #pragma unroll
        for (int kh = 0; kh < 2; ++kh)
            bqf[is][kh] = *(const f16x8*)(qt + ((size_t)(b * N_ + i0 + is * 16 + l15)) * M_
                                          + kh * 32 + quad * 8);

    // ---------------- pass 1: rowmax, j-range split across waves ----------
    float mx[4];
    #pragma unroll
    for (int is = 0; is < 4; ++is) mx[is] = -3.0e38f;
    {
        const f16* kw = kln + (size_t)(w * 512) * 64;
        f16x8 akc[4][2];
        #pragma unroll
        for (int t = 0; t < 4; ++t)
            #pragma unroll
            for (int kh = 0; kh < 2; ++kh)
                akc[t][kh] = *(const f16x8*)(kw + t * 1024 + kh * 512);

        #pragma unroll 2
        for (int jj = 0; jj < 512; jj += 64) {
            f16x8 akn[4][2];
            if (jj + 64 < 512) {
                const f16* kn = kw + (size_t)(jj + 64) * 64;
                #pragma unroll
                for (int t = 0; t < 4; ++t)
                    #pragma unroll
                    for (int kh = 0; kh < 2; ++kh)
                        akn[t][kh] = *(const f16x8*)(kn + t * 1024 + kh * 512);
            }
            #pragma unroll
            for (int t = 0; t < 4; ++t) {
                #pragma unroll
                for (int is = 0; is < 4; ++is) {
                    f32x4 s = {};
                    s = __builtin_amdgcn_mfma_f32_16x16x32_f16(akc[t][0], bqf[is][0], s, 0, 0, 0);
                    s = __builtin_amdgcn_mfma_f32_16x16x32_f16(akc[t][1], bqf[is][1], s, 0, 0, 0);
                    mx[is] = fmaxf(mx[is], fmaxf(fmaxf(s[0], s[1]), fmaxf(s[2], s[3])));
                }
            }
            #pragma unroll
            for (int t = 0; t < 4; ++t)
                #pragma unroll
                for (int kh = 0; kh < 2; ++kh)
                    akc[t][kh] = akn[t][kh];
        }
    }
    #pragma unroll
    for (int is = 0; is < 4; ++is) {
        mx[is] = fmaxf(mx[is], __shfl_xor(mx[is], 16, 64));
        mx[is] = fmaxf(mx[is], __shfl_xor(mx[is], 32, 64));
    }
    if (lane < 16) {
        #pragma unroll
        for (int is = 0; is < 4; ++is) mxs[w][is][lane] = mx[is];
    }
    __syncthreads();
    float m0 = -3.0e38f, m1 = -3.0e38f;
    #pragma unroll
    for (int w2 = 0; w2 < 8; ++w2) {
        m0 = fmaxf(m0, mxs[w2][is0][l15]);
        m1 = fmaxf(m1, mxs[w2][is1][l15]);
    }

    // ---------------- pass 2: pipelined P -> LDS -> PV ---------------------
    f32x4 acc[4][4] = {};                       // [ct][is]
    float lp0 = 0.f, lp1 = 0.f;

    char* pbB = (char*)&Pb[0][0];
    const int swz = (l15 & 7) << 4;
    const int wb0 = ((is0 * 16 + l15) * 128 + (jt * 16 + quad * 4) * 2) ^ swz;
    const int wb1 = wb0 + 2048;                 // is1 row (+16*128); swz < 128
    int rb[4][2];
    #pragma unroll
    for (int is = 0; is < 4; ++is)
        #pragma unroll
        for (int kh = 0; kh < 2; ++kh)
            rb[is][kh] = ((is * 16 + l15) * 128 + kh * 64 + quad * 16) ^ swz;

    const f16* kp = kln + (size_t)(jt * 16) * 64;
    const int cw = w * 4;                       // owned c16-group base

    // prologue: QK(0) -> buf0; prefetch K(1) and V(0)
    f16x8 ak0 = *(const f16x8*)(kp);
    f16x8 ak1 = *(const f16x8*)(kp + 512);
    {
        f32x4 s0 = {}, s1 = {};
        s0 = __builtin_amdgcn_mfma_f32_16x16x32_f16(ak0, bqf[is0][0], s0, 0, 0, 0);
        s0 = __builtin_amdgcn_mfma_f32_16x16x32_f16(ak1, bqf[is0][1], s0, 0, 0, 0);
        s1 = __builtin_amdgcn_mfma_f32_16x16x32_f16(ak0, bqf[is1][0], s1, 0, 0, 0);
        s1 = __builtin_amdgcn_mfma_f32_16x16x32_f16(ak1, bqf[is1][1], s1, 0, 0, 0);
        float p0 = __expf(s0[0] - m0), p1 = __expf(s0[1] - m0);
        float p2 = __expf(s0[2] - m0), p3 = __expf(s0[3] - m0);
        lp0 += (p0 + p1) + (p2 + p3);
        u32x2 pw0 = { pk2(p0, p1), pk2(p2, p3) };
        *(u32x2*)(pbB + wb0) = pw0;
        float q0 = __expf(s1[0] - m1), q1 = __expf(s1[1] - m1);
        float q2 = __expf(s1[2] - m1), q3 = __expf(s1[3] - m1);
        lp1 += (q0 + q1) + (q2 + q3);
        u32x2 pw1 = { pk2(q0, q1), pk2(q2, q3) };
        *(u32x2*)(pbB + wb1) = pw1;
    }
    ak0 = *(const f16x8*)(kp + 4096);
    ak1 = *(const f16x8*)(kp + 4096 + 512);
    f16x8 vc0[4], vc1[4];
    #pragma unroll
    for (int ct = 0; ct < 4; ++ct) {
        vc0[ct] = *(const f16x8*)(vln + (size_t)(cw + ct) * 65536);
        vc1[ct] = *(const f16x8*)(vln + (size_t)(cw + ct) * 65536 + 512);
    }
    __syncthreads();

    #pragma unroll 2
    for (int t = 0; t < 63; ++t) {
        const int cb = (t & 1) * 8192;
        const int nb = ((t + 1) & 1) * 8192;

        // P(t) fragment reads (LDS latency hidden under QK(t+1))
        f16x8 pbf[4][2];
        #pragma unroll
        for (int is = 0; is < 4; ++is)
            #pragma unroll
            for (int kh = 0; kh < 2; ++kh)
                pbf[is][kh] = *(const f16x8*)(pbB + cb + rb[is][kh]);

        // QK(t+1): register-only MFMA
        f32x4 s0 = {}, s1 = {};
        s0 = __builtin_amdgcn_mfma_f32_16x16x32_f16(ak0, bqf[is0][0], s0, 0, 0, 0);
        s0 = __builtin_amdgcn_mfma_f32_16x16x32_f16(ak1, bqf[is0][1], s0, 0, 0, 0);
        s1 = __builtin_amdgcn_mfma_f32_16x16x32_f16(ak0, bqf[is1][0], s1, 0, 0, 0);
        s1 = __builtin_amdgcn_mfma_f32_16x16x32_f16(ak1, bqf[is1][1], s1, 0, 0, 0);

        // prefetch K(t+2)
        if (t + 2 < 64) {
            ak0 = *(const f16x8*)(kp + (size_t)(t + 2) * 4096);
            ak1 = *(const f16x8*)(kp + (size_t)(t + 2) * 4096 + 512);
        }
        // prefetch V(t+1)
        const f16* vt = vln + (size_t)(t + 1) * 1024;
        f16x8 vn0[4], vn1[4];
        #pragma unroll
        for (int ct = 0; ct < 4; ++ct) {
            vn0[ct] = *(const f16x8*)(vt + (size_t)(cw + ct) * 65536);
            vn1[ct] = *(const f16x8*)(vt + (size_t)(cw + ct) * 65536 + 512);
        }

        // exp -> pack -> write P(t+1)
        {
            float p0 = __expf(s0[0] - m0), p1 = __expf(s0[1] - m0);
            float p2 = __expf(s0[2] - m0), p3 = __expf(s0[3] - m0);
            lp0 += (p0 + p1) + (p2 + p3);
            u32x2 pw = { pk2(p0, p1), pk2(p2, p3) };
            *(u32x2*)(pbB + nb + wb0) = pw;
        }
        {
            float q0 = __expf(s1[0] - m1), q1 = __expf(s1[1] - m1);
            float q2 = __expf(s1[2] - m1), q3 = __expf(s1[3] - m1);
            lp1 += (q0 + q1) + (q2 + q3);
            u32x2 pw = { pk2(q0, q1), pk2(q2, q3) };
            *(u32x2*)(pbB + nb + wb1) = pw;
        }

        // PV(t) using V prefetched last interval
        __builtin_amdgcn_s_setprio(1);
        #pragma unroll
        for (int ct = 0; ct < 4; ++ct)
            #pragma unroll
            for (int is = 0; is < 4; ++is)
                acc[ct][is] = __builtin_amdgcn_mfma_f32_16x16x32_f16(vc0[ct], pbf[is][0], acc[ct][is], 0, 0, 0);
        #pragma unroll
        for (int ct = 0; ct < 4; ++ct)
            #pragma unroll
            for (int is = 0; is < 4; ++is)
                acc[ct][is] = __builtin_amdgcn_mfma_f32_16x16x32_f16(vc1[ct], pbf[is][1], acc[ct][is], 0, 0, 0);
        __builtin_amdgcn_s_setprio(0);

        __syncthreads();

        #pragma unroll
        for (int ct = 0; ct < 4; ++ct) { vc0[ct] = vn0[ct]; vc1[ct] = vn1[ct]; }
    }

    // epilogue: PV(63)
    {
        const int cb = (63 & 1) * 8192;
        f16x8 pbf[4][2];
        #pragma unroll
        for (int is = 0; is < 4; ++is)
            #pragma unroll
            for (int kh = 0; kh < 2; ++kh)
                pbf[is][kh] = *(const f16x8*)(pbB + cb + rb[is][kh]);
        #pragma unroll
        for (int ct = 0; ct < 4; ++ct)
            #pragma unroll
            for (int is = 0; is < 4; ++is)
                acc[ct][is] = __builtin_amdgcn_mfma_f32_16x16x32_f16(vc0[ct], pbf[is][0], acc[ct][is], 0, 0, 0);
        #pragma unroll
        for (int ct = 0; ct < 4; ++ct)
            #pragma unroll
            for (int is = 0; is < 4; ++is)
                acc[ct][is] = __builtin_amdgcn_mfma_f32_16x16x32_f16(vc1[ct], pbf[is][1], acc[ct][is], 0, 0, 0);
    }

    // ---------------- l combine + epilogue ---------------------------------
    lp0 += __shfl_xor(lp0, 16, 64);
    lp0 += __shfl_xor(lp0, 32, 64);
    lp1 += __shfl_xor(lp1, 16, 64);
    lp1 += __shfl_xor(lp1, 32, 64);
    if (lane < 16) { lss[w][is0][lane] = lp0; lss[w][is1][lane] = lp1; }
    __syncthreads();

    float linv[4];
    #pragma unroll
    for (int is = 0; is < 4; ++is) {
        const int wb = (is >> 1) * 4;
        float l = (lss[wb + 0][is][l15] + lss[wb + 1][is][l15])
                + (lss[wb + 2][is][l15] + lss[wb + 3][is][l15]);
        linv[is] = 1.0f / l;
    }

    const float g = gamma[0];
    #pragma unroll
    for (int is = 0; is < 4; ++is) {
        const int i = i0 + is * 16 + l15;
        #pragma unroll
        for (int ct = 0; ct < 4; ++ct) {
            #pragma unroll
            for (int r = 0; r < 4; ++r) {
                const int c = w * 64 + ct * 16 + quad * 4 + r;
                const size_t idx = ((size_t)(b * C_ + c)) * N_ + i;
                out[idx] = g * (acc[ct][is][r] * linv[is]) + x[idx];
            }
        }
    }
}

// ---------------------------------------------------------------------------
extern "C" void kernel_launch(void* const* d_in, const int* in_sizes, int n_in,
                              void* d_out, int out_size, void* d_ws, size_t ws_size,
                              hipStream_t stream)
{
    const float* x     = (const float*)d_in[0];
    const float* Wq    = (const float*)d_in[1];
    const float* bq    = (const float*)d_in[2];
    const float* Wk    = (const float*)d_in[3];
    const float* bk    = (const float*)d_in[4];
    const float* Wv    = (const float*)d_in[5];
    const float* bv    = (const float*)d_in[6];
    const float* gamma = (const float*)d_in[7];
    float* out = (float*)d_out;

    char* ws = (char*)d_ws;
    f16* xtf = (f16*)ws;                                   // B*N*C   (16 MB)
    f16* qt  = (f16*)(ws + (size_t)B_ * N_ * C_ * 2);      // B*N*M   ( 2 MB)
    f16* ktf = qt + (size_t)B_ * N_ * M_;                  // B*N*M   ( 2 MB)
    f16* vf  = ktf + (size_t)B_ * N_ * M_;                 // B*C*N   (16 MB)

    transpose_cast<<<dim3(N_ / 64, C_ / 64, B_), 256, 0, stream>>>(x, xtf);
    qkv_gemm<<<dim3(N_ / 128, 10, B_), 512, 0, stream>>>(
        xtf, Wq, bq, Wk, bk, Wv, bv, qt, ktf, vf);
    attn<<<dim3(256), 512, 0, stream>>>(qt, ktf, vf, x, gamma, out);
}

// Round 3
// 224.215 us; speedup vs baseline: 1.6397x; 1.1561x over previous
//
#include <hip/hip_runtime.h>

typedef _Float16 f16;
typedef _Float16 f16x8 __attribute__((ext_vector_type(8)));
typedef float    f32x4 __attribute__((ext_vector_type(4)));
typedef unsigned int u32x2 __attribute__((ext_vector_type(2)));

#define B_ 4
#define C_ 512
#define N_ 4096
#define M_ 64

__device__ __forceinline__ unsigned pk2(float a, float b) {
    union { f16 h[2]; unsigned u; } t;
    t.h[0] = (f16)a; t.h[1] = (f16)b;
    return t.u;
}

// ---------------------------------------------------------------------------
// Kernel W: convert [Wq;Wk;Wv] fp32 -> Wf[640][512] f16 (concatenated rows).
// 40960 threads x 8 elems. Segment boundaries (32768, 65536) are multiples
// of 8, so each thread's 8 elems lie in one segment.
// ---------------------------------------------------------------------------
__global__ __launch_bounds__(256) void wcvt(
    const float* __restrict__ Wq, const float* __restrict__ Wk,
    const float* __restrict__ Wv, f16* __restrict__ Wf)
{
    const int e = (blockIdx.x * 256 + threadIdx.x) * 8;
    const float* src;
    int off;
    if (e < 32768)      { src = Wq; off = e; }
    else if (e < 65536) { src = Wk; off = e - 32768; }
    else                { src = Wv; off = e - 65536; }
    float4 a = *(const float4*)(src + off);
    float4 b = *(const float4*)(src + off + 4);
    f16x8 o;
    o[0]=(f16)a.x; o[1]=(f16)a.y; o[2]=(f16)a.z; o[3]=(f16)a.w;
    o[4]=(f16)b.x; o[5]=(f16)b.y; o[6]=(f16)b.z; o[7]=(f16)b.w;
    *(f16x8*)(Wf + e) = o;
}

// ---------------------------------------------------------------------------
// Kernel A (NEW): fused qkv GEMM straight from x — xtf round-trip eliminated.
//  grid (64 n-tiles, 4 b), 512 thr / 8 waves. Per block: 640 out-rows x 64 n,
//  K=512 in 8 chunks of 64c. x chunk staged fp32 in LDS [64][65] (2-way bank
//  aliasing both phases = free), double-buffered, ONE barrier per chunk
//  (write target = prev iteration's read buffer; barrier separates).
//  Wave w owns rows [80w,80w+80): 5 ot-tiles x 4 n-tiles, 320 MFMA.
//  W read once per block from L2 (f16, pre-converted). Epilogue reuses the
//  validated qt/ktf/vf index formulas; q/k packed into 8B stores.
// ---------------------------------------------------------------------------
__global__ __launch_bounds__(512) void qkv2(
    const f16* __restrict__ Wf, const float* __restrict__ x,
    const float* __restrict__ bq, const float* __restrict__ bk,
    const float* __restrict__ bv,
    f16* __restrict__ qt, f16* __restrict__ ktf, f16* __restrict__ vf)
{
    __shared__ float sX[2][64][65];
    __shared__ float sBias[640];

    const int tid  = threadIdx.x;
    const int w    = tid >> 6;
    const int lane = tid & 63;
    const int l15  = lane & 15;
    const int quad = lane >> 4;
    const int n0   = blockIdx.x * 64;
    const int b    = blockIdx.y;
    const int row0 = w * 80;

    for (int e = tid; e < 640; e += 512)
        sBias[e] = (e < 64) ? bq[e] : (e < 128) ? bk[e - 64] : bv[e - 128];

    // prologue: stage chunk 0
    {
        float4 g[2];
        #pragma unroll
        for (int i = 0; i < 2; ++i) {
            int e = i * 512 + tid, c = e >> 4, n4 = (e & 15) * 4;
            g[i] = *(const float4*)(x + ((size_t)(b * C_ + c)) * N_ + n0 + n4);
        }
        #pragma unroll
        for (int i = 0; i < 2; ++i) {
            int e = i * 512 + tid, c = e >> 4, n4 = (e & 15) * 4;
            sX[0][c][n4 + 0] = g[i].x; sX[0][c][n4 + 1] = g[i].y;
            sX[0][c][n4 + 2] = g[i].z; sX[0][c][n4 + 3] = g[i].w;
        }
    }

    f32x4 acc[5][4] = {};

    for (int t = 0; t < 8; ++t) {
        const int cur = t & 1, nxt = cur ^ 1;

        // issue next x chunk loads early (consumed by ds_write at bottom)
        float4 gn[2];
        if (t < 7) {
            #pragma unroll
            for (int i = 0; i < 2; ++i) {
                int e = i * 512 + tid, c = e >> 4, n4 = (e & 15) * 4;
                gn[i] = *(const float4*)(x + ((size_t)(b * C_ + (t + 1) * 64 + c)) * N_ + n0 + n4);
            }
        }

        __syncthreads();   // sX[cur] writes done; prev readers of sX[nxt] done

        // A fragments (W, f16, L2-hot)
        f16x8 af[5][2];
        #pragma unroll
        for (int ot = 0; ot < 5; ++ot)
            #pragma unroll
            for (int kh = 0; kh < 2; ++kh)
                af[ot][kh] = *(const f16x8*)(Wf + (size_t)(row0 + ot * 16 + l15) * 512
                                             + t * 64 + kh * 32 + quad * 8);

        // B fragments from LDS (fp32 -> f16)
        f16x8 bf[4][2];
        #pragma unroll
        for (int nt = 0; nt < 4; ++nt)
            #pragma unroll
            for (int kh = 0; kh < 2; ++kh) {
                f16x8 o;
                #pragma unroll
                for (int jj = 0; jj < 8; ++jj)
                    o[jj] = (f16)sX[cur][kh * 32 + quad * 8 + jj][nt * 16 + l15];
                bf[nt][kh] = o;
            }

        #pragma unroll
        for (int ot = 0; ot < 5; ++ot)
            #pragma unroll
            for (int kh = 0; kh < 2; ++kh)
                #pragma unroll
                for (int nt = 0; nt < 4; ++nt)
                    acc[ot][nt] = __builtin_amdgcn_mfma_f32_16x16x32_f16(
                        af[ot][kh], bf[nt][kh], acc[ot][nt], 0, 0, 0);

        // stage next chunk (global latency hidden under the MFMAs above)
        if (t < 7) {
            #pragma unroll
            for (int i = 0; i < 2; ++i) {
                int e = i * 512 + tid, c = e >> 4, n4 = (e & 15) * 4;
                sX[nxt][c][n4 + 0] = gn[i].x; sX[nxt][c][n4 + 1] = gn[i].y;
                sX[nxt][c][n4 + 2] = gn[i].z; sX[nxt][c][n4 + 3] = gn[i].w;
            }
        }
    }

    // epilogue: bias + cast + scatter to validated layouts
    #pragma unroll
    for (int ot = 0; ot < 5; ++ot) {
        const int rowBase = row0 + ot * 16;          // multiple of 16
        const int rq = rowBase + quad * 4;
        #pragma unroll
        for (int nt = 0; nt < 4; ++nt) {
            const int n = n0 + nt * 16 + l15;
            union { f16 h[4]; unsigned long long u; } pkv;
            #pragma unroll
            for (int r = 0; r < 4; ++r)
                pkv.h[r] = (f16)(acc[ot][nt][r] + sBias[rq + r]);
            if (rowBase < 64) {
                *(unsigned long long*)(qt + ((size_t)(b * N_ + n)) * M_ + rq) = pkv.u;
            } else if (rowBase < 128) {
                const int ol = rq - 64;
                size_t idx = (((size_t)b * 256 + (n >> 4)) * 2 + (ol >> 5)) * 512
                           + (size_t)((((ol >> 3) & 3) * 16 + (n & 15)) * 8) + (ol & 7);
                *(unsigned long long*)(ktf + idx) = pkv.u;
            } else {
                const int c = rq - 128;
                #pragma unroll
                for (int r = 0; r < 4; ++r) {
                    size_t idx = ((size_t)b * (C_ * N_)) + (size_t)((c + r) >> 4) * 65536
                               + (size_t)(n >> 6) * 1024 + (size_t)((n >> 5) & 1) * 512
                               + (size_t)((((n >> 3) & 3) * 16 + ((c + r) & 15)) * 8) + (n & 7);
                    vf[idx] = pkv.h[r];
                }
            }
        }
    }
}

// ---------------------------------------------------------------------------
// Kernel B: deduplicated, pipelined fused attention (UNCHANGED, validated).
// ---------------------------------------------------------------------------
__global__ __launch_bounds__(512, 2) void attn(
    const f16* __restrict__ qt, const f16* __restrict__ ktf,
    const f16* __restrict__ vf, const float* __restrict__ x,
    const float* __restrict__ gamma, float* __restrict__ out)
{
    __shared__ __align__(16) char Pb[2][8192];   // P: 64 i x 64 j f16, dbuf
    __shared__ float mxs[8][4][16];
    __shared__ float lss[8][4][16];

    const int tid  = threadIdx.x;
    const int w    = tid >> 6;                  // 0..7
    const int lane = tid & 63;
    const int l15  = lane & 15;
    const int quad = lane >> 4;
    const int jt   = w & 3;                     // owned QK j-subtile (pass 2)
    const int ish  = w >> 2;                    // owned is-pair {2ish, 2ish+1}
    const int is0  = ish * 2, is1 = is0 + 1;

    const int lin  = blockIdx.x;                // 0..255
    const int b    = (lin & 7) >> 1;            // XCD-pinned batch
    const int iblk = ((lin >> 3) << 1) | (lin & 1);  // 0..63
    const int i0   = iblk * 64;

    const f16* kln = ktf + (size_t)b * (N_ * M_) + lane * 8;
    const f16* vln = vf  + (size_t)b * (C_ * N_) + lane * 8;

    // Q fragments, all 4 is tiles (pass 1 needs all four)
    f16x8 bqf[4][2];
    #pragma unroll
    for (int is = 0; is < 4; ++is)
        #pragma unroll
        for (int kh = 0; kh < 2; ++kh)
            bqf[is][kh] = *(const f16x8*)(qt + ((size_t)(b * N_ + i0 + is * 16 + l15)) * M_
                                          + kh * 32 + quad * 8);

    // ---------------- pass 1: rowmax, j-range split across waves ----------
    float mx[4];
    #pragma unroll
    for (int is = 0; is < 4; ++is) mx[is] = -3.0e38f;
    {
        const f16* kw = kln + (size_t)(w * 512) * 64;
        f16x8 akc[4][2];
        #pragma unroll
        for (int t = 0; t < 4; ++t)
            #pragma unroll
            for (int kh = 0; kh < 2; ++kh)
                akc[t][kh] = *(const f16x8*)(kw + t * 1024 + kh * 512);

        #pragma unroll 2
        for (int jj = 0; jj < 512; jj += 64) {
            f16x8 akn[4][2];
            if (jj + 64 < 512) {
                const f16* kn = kw + (size_t)(jj + 64) * 64;
                #pragma unroll
                for (int t = 0; t < 4; ++t)
                    #pragma unroll
                    for (int kh = 0; kh < 2; ++kh)
                        akn[t][kh] = *(const f16x8*)(kn + t * 1024 + kh * 512);
            }
            #pragma unroll
            for (int t = 0; t < 4; ++t) {
                #pragma unroll
                for (int is = 0; is < 4; ++is) {
                    f32x4 s = {};
                    s = __builtin_amdgcn_mfma_f32_16x16x32_f16(akc[t][0], bqf[is][0], s, 0, 0, 0);
                    s = __builtin_amdgcn_mfma_f32_16x16x32_f16(akc[t][1], bqf[is][1], s, 0, 0, 0);
                    mx[is] = fmaxf(mx[is], fmaxf(fmaxf(s[0], s[1]), fmaxf(s[2], s[3])));
                }
            }
            #pragma unroll
            for (int t = 0; t < 4; ++t)
                #pragma unroll
                for (int kh = 0; kh < 2; ++kh)
                    akc[t][kh] = akn[t][kh];
        }
    }
    #pragma unroll
    for (int is = 0; is < 4; ++is) {
        mx[is] = fmaxf(mx[is], __shfl_xor(mx[is], 16, 64));
        mx[is] = fmaxf(mx[is], __shfl_xor(mx[is], 32, 64));
    }
    if (lane < 16) {
        #pragma unroll
        for (int is = 0; is < 4; ++is) mxs[w][is][lane] = mx[is];
    }
    __syncthreads();
    float m0 = -3.0e38f, m1 = -3.0e38f;
    #pragma unroll
    for (int w2 = 0; w2 < 8; ++w2) {
        m0 = fmaxf(m0, mxs[w2][is0][l15]);
        m1 = fmaxf(m1, mxs[w2][is1][l15]);
    }

    // ---------------- pass 2: pipelined P -> LDS -> PV ---------------------
    f32x4 acc[4][4] = {};                       // [ct][is]
    float lp0 = 0.f, lp1 = 0.f;

    char* pbB = (char*)&Pb[0][0];
    const int swz = (l15 & 7) << 4;
    const int wb0 = ((is0 * 16 + l15) * 128 + (jt * 16 + quad * 4) * 2) ^ swz;
    const int wb1 = wb0 + 2048;                 // is1 row (+16*128); swz < 128
    int rb[4][2];
    #pragma unroll
    for (int is = 0; is < 4; ++is)
        #pragma unroll
        for (int kh = 0; kh < 2; ++kh)
            rb[is][kh] = ((is * 16 + l15) * 128 + kh * 64 + quad * 16) ^ swz;

    const f16* kp = kln + (size_t)(jt * 16) * 64;
    const int cw = w * 4;                       // owned c16-group base

    // prologue: QK(0) -> buf0; prefetch K(1) and V(0)
    f16x8 ak0 = *(const f16x8*)(kp);
    f16x8 ak1 = *(const f16x8*)(kp + 512);
    {
        f32x4 s0 = {}, s1 = {};
        s0 = __builtin_amdgcn_mfma_f32_16x16x32_f16(ak0, bqf[is0][0], s0, 0, 0, 0);
        s0 = __builtin_amdgcn_mfma_f32_16x16x32_f16(ak1, bqf[is0][1], s0, 0, 0, 0);
        s1 = __builtin_amdgcn_mfma_f32_16x16x32_f16(ak0, bqf[is1][0], s1, 0, 0, 0);
        s1 = __builtin_amdgcn_mfma_f32_16x16x32_f16(ak1, bqf[is1][1], s1, 0, 0, 0);
        float p0 = __expf(s0[0] - m0), p1 = __expf(s0[1] - m0);
        float p2 = __expf(s0[2] - m0), p3 = __expf(s0[3] - m0);
        lp0 += (p0 + p1) + (p2 + p3);
        u32x2 pw0 = { pk2(p0, p1), pk2(p2, p3) };
        *(u32x2*)(pbB + wb0) = pw0;
        float q0 = __expf(s1[0] - m1), q1 = __expf(s1[1] - m1);
        float q2 = __expf(s1[2] - m1), q3 = __expf(s1[3] - m1);
        lp1 += (q0 + q1) + (q2 + q3);
        u32x2 pw1 = { pk2(q0, q1), pk2(q2, q3) };
        *(u32x2*)(pbB + wb1) = pw1;
    }
    ak0 = *(const f16x8*)(kp + 4096);
    ak1 = *(const f16x8*)(kp + 4096 + 512);
    f16x8 vc0[4], vc1[4];
    #pragma unroll
    for (int ct = 0; ct < 4; ++ct) {
        vc0[ct] = *(const f16x8*)(vln + (size_t)(cw + ct) * 65536);
        vc1[ct] = *(const f16x8*)(vln + (size_t)(cw + ct) * 65536 + 512);
    }
    __syncthreads();

    #pragma unroll 2
    for (int t = 0; t < 63; ++t) {
        const int cb = (t & 1) * 8192;
        const int nb = ((t + 1) & 1) * 8192;

        // P(t) fragment reads (LDS latency hidden under QK(t+1))
        f16x8 pbf[4][2];
        #pragma unroll
        for (int is = 0; is < 4; ++is)
            #pragma unroll
            for (int kh = 0; kh < 2; ++kh)
                pbf[is][kh] = *(const f16x8*)(pbB + cb + rb[is][kh]);

        // QK(t+1): register-only MFMA
        f32x4 s0 = {}, s1 = {};
        s0 = __builtin_amdgcn_mfma_f32_16x16x32_f16(ak0, bqf[is0][0], s0, 0, 0, 0);
        s0 = __builtin_amdgcn_mfma_f32_16x16x32_f16(ak1, bqf[is0][1], s0, 0, 0, 0);
        s1 = __builtin_amdgcn_mfma_f32_16x16x32_f16(ak0, bqf[is1][0], s1, 0, 0, 0);
        s1 = __builtin_amdgcn_mfma_f32_16x16x32_f16(ak1, bqf[is1][1], s1, 0, 0, 0);

        // prefetch K(t+2)
        if (t + 2 < 64) {
            ak0 = *(const f16x8*)(kp + (size_t)(t + 2) * 4096);
            ak1 = *(const f16x8*)(kp + (size_t)(t + 2) * 4096 + 512);
        }
        // prefetch V(t+1)
        const f16* vt = vln + (size_t)(t + 1) * 1024;
        f16x8 vn0[4], vn1[4];
        #pragma unroll
        for (int ct = 0; ct < 4; ++ct) {
            vn0[ct] = *(const f16x8*)(vt + (size_t)(cw + ct) * 65536);
            vn1[ct] = *(const f16x8*)(vt + (size_t)(cw + ct) * 65536 + 512);
        }

        // exp -> pack -> write P(t+1)
        {
            float p0 = __expf(s0[0] - m0), p1 = __expf(s0[1] - m0);
            float p2 = __expf(s0[2] - m0), p3 = __expf(s0[3] - m0);
            lp0 += (p0 + p1) + (p2 + p3);
            u32x2 pw = { pk2(p0, p1), pk2(p2, p3) };
            *(u32x2*)(pbB + nb + wb0) = pw;
        }
        {
            float q0 = __expf(s1[0] - m1), q1 = __expf(s1[1] - m1);
            float q2 = __expf(s1[2] - m1), q3 = __expf(s1[3] - m1);
            lp1 += (q0 + q1) + (q2 + q3);
            u32x2 pw = { pk2(q0, q1), pk2(q2, q3) };
            *(u32x2*)(pbB + nb + wb1) = pw;
        }

        // PV(t) using V prefetched last interval
        __builtin_amdgcn_s_setprio(1);
        #pragma unroll
        for (int ct = 0; ct < 4; ++ct)
            #pragma unroll
            for (int is = 0; is < 4; ++is)
                acc[ct][is] = __builtin_amdgcn_mfma_f32_16x16x32_f16(vc0[ct], pbf[is][0], acc[ct][is], 0, 0, 0);
        #pragma unroll
        for (int ct = 0; ct < 4; ++ct)
            #pragma unroll
            for (int is = 0; is < 4; ++is)
                acc[ct][is] = __builtin_amdgcn_mfma_f32_16x16x32_f16(vc1[ct], pbf[is][1], acc[ct][is], 0, 0, 0);
        __builtin_amdgcn_s_setprio(0);

        __syncthreads();

        #pragma unroll
        for (int ct = 0; ct < 4; ++ct) { vc0[ct] = vn0[ct]; vc1[ct] = vn1[ct]; }
    }

    // epilogue: PV(63)
    {
        const int cb = (63 & 1) * 8192;
        f16x8 pbf[4][2];
        #pragma unroll
        for (int is = 0; is < 4; ++is)
            #pragma unroll
            for (int kh = 0; kh < 2; ++kh)
                pbf[is][kh] = *(const f16x8*)(pbB + cb + rb[is][kh]);
        #pragma unroll
        for (int ct = 0; ct < 4; ++ct)
            #pragma unroll
            for (int is = 0; is < 4; ++is)
                acc[ct][is] = __builtin_amdgcn_mfma_f32_16x16x32_f16(vc0[ct], pbf[is][0], acc[ct][is], 0, 0, 0);
        #pragma unroll
        for (int ct = 0; ct < 4; ++ct)
            #pragma unroll
            for (int is = 0; is < 4; ++is)
                acc[ct][is] = __builtin_amdgcn_mfma_f32_16x16x32_f16(vc1[ct], pbf[is][1], acc[ct][is], 0, 0, 0);
    }

    // ---------------- l combine + epilogue ---------------------------------
    lp0 += __shfl_xor(lp0, 16, 64);
    lp0 += __shfl_xor(lp0, 32, 64);
    lp1 += __shfl_xor(lp1, 16, 64);
    lp1 += __shfl_xor(lp1, 32, 64);
    if (lane < 16) { lss[w][is0][lane] = lp0; lss[w][is1][lane] = lp1; }
    __syncthreads();

    float linv[4];
    #pragma unroll
    for (int is = 0; is < 4; ++is) {
        const int wb = (is >> 1) * 4;
        float l = (lss[wb + 0][is][l15] + lss[wb + 1][is][l15])
                + (lss[wb + 2][is][l15] + lss[wb + 3][is][l15]);
        linv[is] = 1.0f / l;
    }

    const float g = gamma[0];
    #pragma unroll
    for (int is = 0; is < 4; ++is) {
        const int i = i0 + is * 16 + l15;
        #pragma unroll
        for (int ct = 0; ct < 4; ++ct) {
            #pragma unroll
            for (int r = 0; r < 4; ++r) {
                const int c = w * 64 + ct * 16 + quad * 4 + r;
                const size_t idx = ((size_t)(b * C_ + c)) * N_ + i;
                out[idx] = g * (acc[ct][is][r] * linv[is]) + x[idx];
            }
        }
    }
}

// ---------------------------------------------------------------------------
extern "C" void kernel_launch(void* const* d_in, const int* in_sizes, int n_in,
                              void* d_out, int out_size, void* d_ws, size_t ws_size,
                              hipStream_t stream)
{
    const float* x     = (const float*)d_in[0];
    const float* Wq    = (const float*)d_in[1];
    const float* bq    = (const float*)d_in[2];
    const float* Wk    = (const float*)d_in[3];
    const float* bk    = (const float*)d_in[4];
    const float* Wv    = (const float*)d_in[5];
    const float* bv    = (const float*)d_in[6];
    const float* gamma = (const float*)d_in[7];
    float* out = (float*)d_out;

    char* ws = (char*)d_ws;
    f16* qt  = (f16*)ws;                                   // B*N*M   ( 2 MB)
    f16* ktf = qt + (size_t)B_ * N_ * M_;                  // B*N*M   ( 2 MB)
    f16* vf  = ktf + (size_t)B_ * N_ * M_;                 // B*C*N   (16 MB)
    f16* Wf  = vf + (size_t)B_ * C_ * N_;                  // 640*512 (0.6 MB)

    wcvt<<<dim3(160), 256, 0, stream>>>(Wq, Wk, Wv, Wf);
    qkv2<<<dim3(N_ / 64, B_), 512, 0, stream>>>(Wf, x, bq, bk, bv, qt, ktf, vf);
    attn<<<dim3(256), 512, 0, stream>>>(qt, ktf, vf, x, gamma, out);
}

// Round 4
// 215.203 us; speedup vs baseline: 1.7084x; 1.0419x over previous
//
#include <hip/hip_runtime.h>

typedef _Float16 f16;
typedef _Float16 f16x8 __attribute__((ext_vector_type(8)));
typedef float    f32x4 __attribute__((ext_vector_type(4)));
typedef unsigned int u32x2 __attribute__((ext_vector_type(2)));

#define B_ 4
#define C_ 512
#define N_ 4096
#define M_ 64

__device__ __forceinline__ unsigned pk2(float a, float b) {
    union { f16 h[2]; unsigned u; } t;
    t.h[0] = (f16)a; t.h[1] = (f16)b;
    return t.u;
}

// ---------------------------------------------------------------------------
// Kernel W: convert [Wq;Wk;Wv] fp32 -> Wf[640][512] f16 (concatenated rows).
// ---------------------------------------------------------------------------
__global__ __launch_bounds__(256) void wcvt(
    const float* __restrict__ Wq, const float* __restrict__ Wk,
    const float* __restrict__ Wv, f16* __restrict__ Wf)
{
    const int e = (blockIdx.x * 256 + threadIdx.x) * 8;
    const float* src;
    int off;
    if (e < 32768)      { src = Wq; off = e; }
    else if (e < 65536) { src = Wk; off = e - 32768; }
    else                { src = Wv; off = e - 65536; }
    float4 a = *(const float4*)(src + off);
    float4 b = *(const float4*)(src + off + 4);
    f16x8 o;
    o[0]=(f16)a.x; o[1]=(f16)a.y; o[2]=(f16)a.z; o[3]=(f16)a.w;
    o[4]=(f16)b.x; o[5]=(f16)b.y; o[6]=(f16)b.z; o[7]=(f16)b.w;
    *(f16x8*)(Wf + e) = o;
}

// ---------------------------------------------------------------------------
// Kernel A (R4): fused qkv GEMM from x. LDS now stores the x chunk as f16 in
// a [64n][64c] XOR-swizzled tile (byte ^= (n&7)<<4):
//   - write: thread loads x[c0..c0+7][n0+lane] (8 coalesced dwords), cvt once,
//     ONE swizzled ds_write_b128 (uniform 16B-slot spread = b128 floor).
//   - read: B fragment (8 consecutive c at fixed n) = ONE swizzled
//     ds_read_b128 (was 64 scalar ds_read_b32 + 64 cvt -> the m80 failure).
// W fragments register-prefetched one chunk ahead (L2 latency ~200cyc,
// only 2 waves/SIMD available to hide it).
// ---------------------------------------------------------------------------
__global__ __launch_bounds__(512) void qkv2(
    const f16* __restrict__ Wf, const float* __restrict__ x,
    const float* __restrict__ bq, const float* __restrict__ bk,
    const float* __restrict__ bv,
    f16* __restrict__ qt, f16* __restrict__ ktf, f16* __restrict__ vf)
{
    __shared__ __align__(16) char sH[2][8192];   // 64n x 64c f16, swizzled
    __shared__ float sBias[640];

    const int tid  = threadIdx.x;
    const int w    = tid >> 6;
    const int lane = tid & 63;
    const int l15  = lane & 15;
    const int quad = lane >> 4;
    const int n0   = blockIdx.x * 64;
    const int b    = blockIdx.y;
    const int row0 = w * 80;

    for (int e = tid; e < 640; e += 512)
        sBias[e] = (e < 64) ? bq[e] : (e < 128) ? bk[e - 64] : bv[e - 128];

    // swizzled staging address: (n=lane, c-block=w)
    const int wbyte = (lane * 128 + w * 16) ^ ((lane & 7) << 4);
    // swizzled fragment-read addresses: (nt, kh)
    int rbyte[4][2];
    #pragma unroll
    for (int nt = 0; nt < 4; ++nt) {
        const int n = nt * 16 + l15;
        #pragma unroll
        for (int kh = 0; kh < 2; ++kh)
            rbyte[nt][kh] = (n * 128 + kh * 64 + quad * 16) ^ ((n & 7) << 4);
    }

    const float* xg = x + (size_t)b * (C_ * N_) + n0 + lane;   // x[b][c][n0+lane]
    const f16*   wp = Wf + (size_t)row0 * 512 + quad * 8;

    // prologue: stage chunk 0; prefetch W fragments for chunk 0
    {
        float g[8];
        #pragma unroll
        for (int u = 0; u < 8; ++u)
            g[u] = xg[(size_t)(w * 8 + u) * N_];
        f16x8 h;
        #pragma unroll
        for (int u = 0; u < 8; ++u) h[u] = (f16)g[u];
        *(f16x8*)(&sH[0][0] + wbyte) = h;
    }
    f16x8 afc[5][2];
    #pragma unroll
    for (int ot = 0; ot < 5; ++ot)
        #pragma unroll
        for (int kh = 0; kh < 2; ++kh)
            afc[ot][kh] = *(const f16x8*)(wp + (size_t)(ot * 16 + l15) * 512 + kh * 32);

    f32x4 acc[5][4] = {};

    for (int t = 0; t < 8; ++t) {
        char* sc = &sH[t & 1][0];
        char* sn = &sH[(t & 1) ^ 1][0];

        // issue next-chunk x loads + next-chunk W loads (latency hidden under
        // this chunk's MFMAs)
        float gn[8];
        f16x8 afn[5][2];
        if (t < 7) {
            #pragma unroll
            for (int u = 0; u < 8; ++u)
                gn[u] = xg[(size_t)((t + 1) * 64 + w * 8 + u) * N_];
            #pragma unroll
            for (int ot = 0; ot < 5; ++ot)
                #pragma unroll
                for (int kh = 0; kh < 2; ++kh)
                    afn[ot][kh] = *(const f16x8*)(wp + (size_t)(ot * 16 + l15) * 512
                                                  + (t + 1) * 64 + kh * 32);
        }

        __syncthreads();   // sH[cur] writes visible; prev readers of sH[nxt] done

        // B fragments: one swizzled b128 each
        f16x8 bf[4][2];
        #pragma unroll
        for (int nt = 0; nt < 4; ++nt)
            #pragma unroll
            for (int kh = 0; kh < 2; ++kh)
                bf[nt][kh] = *(const f16x8*)(sc + rbyte[nt][kh]);

        #pragma unroll
        for (int ot = 0; ot < 5; ++ot)
            #pragma unroll
            for (int kh = 0; kh < 2; ++kh)
                #pragma unroll
                for (int nt = 0; nt < 4; ++nt)
                    acc[ot][nt] = __builtin_amdgcn_mfma_f32_16x16x32_f16(
                        afc[ot][kh], bf[nt][kh], acc[ot][nt], 0, 0, 0);

        // stage next chunk (cvt once, one b128 write)
        if (t < 7) {
            f16x8 h;
            #pragma unroll
            for (int u = 0; u < 8; ++u) h[u] = (f16)gn[u];
            *(f16x8*)(sn + wbyte) = h;
            #pragma unroll
            for (int ot = 0; ot < 5; ++ot)
                #pragma unroll
                for (int kh = 0; kh < 2; ++kh)
                    afc[ot][kh] = afn[ot][kh];
        }
    }

    // epilogue: bias + cast + scatter to validated layouts
    #pragma unroll
    for (int ot = 0; ot < 5; ++ot) {
        const int rowBase = row0 + ot * 16;          // multiple of 16
        const int rq = rowBase + quad * 4;
        #pragma unroll
        for (int nt = 0; nt < 4; ++nt) {
            const int n = n0 + nt * 16 + l15;
            union { f16 h[4]; unsigned long long u; } pkv;
            #pragma unroll
            for (int r = 0; r < 4; ++r)
                pkv.h[r] = (f16)(acc[ot][nt][r] + sBias[rq + r]);
            if (rowBase < 64) {
                *(unsigned long long*)(qt + ((size_t)(b * N_ + n)) * M_ + rq) = pkv.u;
            } else if (rowBase < 128) {
                const int ol = rq - 64;
                size_t idx = (((size_t)b * 256 + (n >> 4)) * 2 + (ol >> 5)) * 512
                           + (size_t)((((ol >> 3) & 3) * 16 + (n & 15)) * 8) + (ol & 7);
                *(unsigned long long*)(ktf + idx) = pkv.u;
            } else {
                const int c = rq - 128;
                #pragma unroll
                for (int r = 0; r < 4; ++r) {
                    size_t idx = ((size_t)b * (C_ * N_)) + (size_t)((c + r) >> 4) * 65536
                               + (size_t)(n >> 6) * 1024 + (size_t)((n >> 5) & 1) * 512
                               + (size_t)((((n >> 3) & 3) * 16 + ((c + r) & 15)) * 8) + (n & 7);
                    vf[idx] = pkv.h[r];
                }
            }
        }
    }
}

// ---------------------------------------------------------------------------
// Kernel B: deduplicated, pipelined fused attention (UNCHANGED, validated).
// ---------------------------------------------------------------------------
__global__ __launch_bounds__(512, 2) void attn(
    const f16* __restrict__ qt, const f16* __restrict__ ktf,
    const f16* __restrict__ vf, const float* __restrict__ x,
    const float* __restrict__ gamma, float* __restrict__ out)
{
    __shared__ __align__(16) char Pb[2][8192];   // P: 64 i x 64 j f16, dbuf
    __shared__ float mxs[8][4][16];
    __shared__ float lss[8][4][16];

    const int tid  = threadIdx.x;
    const int w    = tid >> 6;                  // 0..7
    const int lane = tid & 63;
    const int l15  = lane & 15;
    const int quad = lane >> 4;
    const int jt   = w & 3;                     // owned QK j-subtile (pass 2)
    const int ish  = w >> 2;                    // owned is-pair {2ish, 2ish+1}
    const int is0  = ish * 2, is1 = is0 + 1;

    const int lin  = blockIdx.x;                // 0..255
    const int b    = (lin & 7) >> 1;            // XCD-pinned batch
    const int iblk = ((lin >> 3) << 1) | (lin & 1);  // 0..63
    const int i0   = iblk * 64;

    const f16* kln = ktf + (size_t)b * (N_ * M_) + lane * 8;
    const f16* vln = vf  + (size_t)b * (C_ * N_) + lane * 8;

    // Q fragments, all 4 is tiles (pass 1 needs all four)
    f16x8 bqf[4][2];
    #pragma unroll
    for (int is = 0; is < 4; ++is)
        #pragma unroll
        for (int kh = 0; kh < 2; ++kh)
            bqf[is][kh] = *(const f16x8*)(qt + ((size_t)(b * N_ + i0 + is * 16 + l15)) * M_
                                          + kh * 32 + quad * 8);

    // ---------------- pass 1: rowmax, j-range split across waves ----------
    float mx[4];
    #pragma unroll
    for (int is = 0; is < 4; ++is) mx[is] = -3.0e38f;
    {
        const f16* kw = kln + (size_t)(w * 512) * 64;
        f16x8 akc[4][2];
        #pragma unroll
        for (int t = 0; t < 4; ++t)
            #pragma unroll
            for (int kh = 0; kh < 2; ++kh)
                akc[t][kh] = *(const f16x8*)(kw + t * 1024 + kh * 512);

        #pragma unroll 2
        for (int jj = 0; jj < 512; jj += 64) {
            f16x8 akn[4][2];
            if (jj + 64 < 512) {
                const f16* kn = kw + (size_t)(jj + 64) * 64;
                #pragma unroll
                for (int t = 0; t < 4; ++t)
                    #pragma unroll
                    for (int kh = 0; kh < 2; ++kh)
                        akn[t][kh] = *(const f16x8*)(kn + t * 1024 + kh * 512);
            }
            #pragma unroll
            for (int t = 0; t < 4; ++t) {
                #pragma unroll
                for (int is = 0; is < 4; ++is) {
                    f32x4 s = {};
                    s = __builtin_amdgcn_mfma_f32_16x16x32_f16(akc[t][0], bqf[is][0], s, 0, 0, 0);
                    s = __builtin_amdgcn_mfma_f32_16x16x32_f16(akc[t][1], bqf[is][1], s, 0, 0, 0);
                    mx[is] = fmaxf(mx[is], fmaxf(fmaxf(s[0], s[1]), fmaxf(s[2], s[3])));
                }
            }
            #pragma unroll
            for (int t = 0; t < 4; ++t)
                #pragma unroll
                for (int kh = 0; kh < 2; ++kh)
                    akc[t][kh] = akn[t][kh];
        }
    }
    #pragma unroll
    for (int is = 0; is < 4; ++is) {
        mx[is] = fmaxf(mx[is], __shfl_xor(mx[is], 16, 64));
        mx[is] = fmaxf(mx[is], __shfl_xor(mx[is], 32, 64));
    }
    if (lane < 16) {
        #pragma unroll
        for (int is = 0; is < 4; ++is) mxs[w][is][lane] = mx[is];
    }
    __syncthreads();
    float m0 = -3.0e38f, m1 = -3.0e38f;
    #pragma unroll
    for (int w2 = 0; w2 < 8; ++w2) {
        m0 = fmaxf(m0, mxs[w2][is0][l15]);
        m1 = fmaxf(m1, mxs[w2][is1][l15]);
    }

    // ---------------- pass 2: pipelined P -> LDS -> PV ---------------------
    f32x4 acc[4][4] = {};                       // [ct][is]
    float lp0 = 0.f, lp1 = 0.f;

    char* pbB = (char*)&Pb[0][0];
    const int swz = (l15 & 7) << 4;
    const int wb0 = ((is0 * 16 + l15) * 128 + (jt * 16 + quad * 4) * 2) ^ swz;
    const int wb1 = wb0 + 2048;                 // is1 row (+16*128); swz < 128
    int rb[4][2];
    #pragma unroll
    for (int is = 0; is < 4; ++is)
        #pragma unroll
        for (int kh = 0; kh < 2; ++kh)
            rb[is][kh] = ((is * 16 + l15) * 128 + kh * 64 + quad * 16) ^ swz;

    const f16* kp = kln + (size_t)(jt * 16) * 64;
    const int cw = w * 4;                       // owned c16-group base

    // prologue: QK(0) -> buf0; prefetch K(1) and V(0)
    f16x8 ak0 = *(const f16x8*)(kp);
    f16x8 ak1 = *(const f16x8*)(kp + 512);
    {
        f32x4 s0 = {}, s1 = {};
        s0 = __builtin_amdgcn_mfma_f32_16x16x32_f16(ak0, bqf[is0][0], s0, 0, 0, 0);
        s0 = __builtin_amdgcn_mfma_f32_16x16x32_f16(ak1, bqf[is0][1], s0, 0, 0, 0);
        s1 = __builtin_amdgcn_mfma_f32_16x16x32_f16(ak0, bqf[is1][0], s1, 0, 0, 0);
        s1 = __builtin_amdgcn_mfma_f32_16x16x32_f16(ak1, bqf[is1][1], s1, 0, 0, 0);
        float p0 = __expf(s0[0] - m0), p1 = __expf(s0[1] - m0);
        float p2 = __expf(s0[2] - m0), p3 = __expf(s0[3] - m0);
        lp0 += (p0 + p1) + (p2 + p3);
        u32x2 pw0 = { pk2(p0, p1), pk2(p2, p3) };
        *(u32x2*)(pbB + wb0) = pw0;
        float q0 = __expf(s1[0] - m1), q1 = __expf(s1[1] - m1);
        float q2 = __expf(s1[2] - m1), q3 = __expf(s1[3] - m1);
        lp1 += (q0 + q1) + (q2 + q3);
        u32x2 pw1 = { pk2(q0, q1), pk2(q2, q3) };
        *(u32x2*)(pbB + wb1) = pw1;
    }
    ak0 = *(const f16x8*)(kp + 4096);
    ak1 = *(const f16x8*)(kp + 4096 + 512);
    f16x8 vc0[4], vc1[4];
    #pragma unroll
    for (int ct = 0; ct < 4; ++ct) {
        vc0[ct] = *(const f16x8*)(vln + (size_t)(cw + ct) * 65536);
        vc1[ct] = *(const f16x8*)(vln + (size_t)(cw + ct) * 65536 + 512);
    }
    __syncthreads();

    #pragma unroll 2
    for (int t = 0; t < 63; ++t) {
        const int cb = (t & 1) * 8192;
        const int nb = ((t + 1) & 1) * 8192;

        // P(t) fragment reads (LDS latency hidden under QK(t+1))
        f16x8 pbf[4][2];
        #pragma unroll
        for (int is = 0; is < 4; ++is)
            #pragma unroll
            for (int kh = 0; kh < 2; ++kh)
                pbf[is][kh] = *(const f16x8*)(pbB + cb + rb[is][kh]);

        // QK(t+1): register-only MFMA
        f32x4 s0 = {}, s1 = {};
        s0 = __builtin_amdgcn_mfma_f32_16x16x32_f16(ak0, bqf[is0][0], s0, 0, 0, 0);
        s0 = __builtin_amdgcn_mfma_f32_16x16x32_f16(ak1, bqf[is0][1], s0, 0, 0, 0);
        s1 = __builtin_amdgcn_mfma_f32_16x16x32_f16(ak0, bqf[is1][0], s1, 0, 0, 0);
        s1 = __builtin_amdgcn_mfma_f32_16x16x32_f16(ak1, bqf[is1][1], s1, 0, 0, 0);

        // prefetch K(t+2)
        if (t + 2 < 64) {
            ak0 = *(const f16x8*)(kp + (size_t)(t + 2) * 4096);
            ak1 = *(const f16x8*)(kp + (size_t)(t + 2) * 4096 + 512);
        }
        // prefetch V(t+1)
        const f16* vt = vln + (size_t)(t + 1) * 1024;
        f16x8 vn0[4], vn1[4];
        #pragma unroll
        for (int ct = 0; ct < 4; ++ct) {
            vn0[ct] = *(const f16x8*)(vt + (size_t)(cw + ct) * 65536);
            vn1[ct] = *(const f16x8*)(vt + (size_t)(cw + ct) * 65536 + 512);
        }

        // exp -> pack -> write P(t+1)
        {
            float p0 = __expf(s0[0] - m0), p1 = __expf(s0[1] - m0);
            float p2 = __expf(s0[2] - m0), p3 = __expf(s0[3] - m0);
            lp0 += (p0 + p1) + (p2 + p3);
            u32x2 pw = { pk2(p0, p1), pk2(p2, p3) };
            *(u32x2*)(pbB + nb + wb0) = pw;
        }
        {
            float q0 = __expf(s1[0] - m1), q1 = __expf(s1[1] - m1);
            float q2 = __expf(s1[2] - m1), q3 = __expf(s1[3] - m1);
            lp1 += (q0 + q1) + (q2 + q3);
            u32x2 pw = { pk2(q0, q1), pk2(q2, q3) };
            *(u32x2*)(pbB + nb + wb1) = pw;
        }

        // PV(t) using V prefetched last interval
        __builtin_amdgcn_s_setprio(1);
        #pragma unroll
        for (int ct = 0; ct < 4; ++ct)
            #pragma unroll
            for (int is = 0; is < 4; ++is)
                acc[ct][is] = __builtin_amdgcn_mfma_f32_16x16x32_f16(vc0[ct], pbf[is][0], acc[ct][is], 0, 0, 0);
        #pragma unroll
        for (int ct = 0; ct < 4; ++ct)
            #pragma unroll
            for (int is = 0; is < 4; ++is)
                acc[ct][is] = __builtin_amdgcn_mfma_f32_16x16x32_f16(vc1[ct], pbf[is][1], acc[ct][is], 0, 0, 0);
        __builtin_amdgcn_s_setprio(0);

        __syncthreads();

        #pragma unroll
        for (int ct = 0; ct < 4; ++ct) { vc0[ct] = vn0[ct]; vc1[ct] = vn1[ct]; }
    }

    // epilogue: PV(63)
    {
        const int cb = (63 & 1) * 8192;
        f16x8 pbf[4][2];
        #pragma unroll
        for (int is = 0; is < 4; ++is)
            #pragma unroll
            for (int kh = 0; kh < 2; ++kh)
                pbf[is][kh] = *(const f16x8*)(pbB + cb + rb[is][kh]);
        #pragma unroll
        for (int ct = 0; ct < 4; ++ct)
            #pragma unroll
            for (int is = 0; is < 4; ++is)
                acc[ct][is] = __builtin_amdgcn_mfma_f32_16x16x32_f16(vc0[ct], pbf[is][0], acc[ct][is], 0, 0, 0);
        #pragma unroll
        for (int ct = 0; ct < 4; ++ct)
            #pragma unroll
            for (int is = 0; is < 4; ++is)
                acc[ct][is] = __builtin_amdgcn_mfma_f32_16x16x32_f16(vc1[ct], pbf[is][1], acc[ct][is], 0, 0, 0);
    }

    // ---------------- l combine + epilogue ---------------------------------
    lp0 += __shfl_xor(lp0, 16, 64);
    lp0 += __shfl_xor(lp0, 32, 64);
    lp1 += __shfl_xor(lp1, 16, 64);
    lp1 += __shfl_xor(lp1, 32, 64);
    if (lane < 16) { lss[w][is0][lane] = lp0; lss[w][is1][lane] = lp1; }
    __syncthreads();

    float linv[4];
    #pragma unroll
    for (int is = 0; is < 4; ++is) {
        const int wb = (is >> 1) * 4;
        float l = (lss[wb + 0][is][l15] + lss[wb + 1][is][l15])
                + (lss[wb + 2][is][l15] + lss[wb + 3][is][l15]);
        linv[is] = 1.0f / l;
    }

    const float g = gamma[0];
    #pragma unroll
    for (int is = 0; is < 4; ++is) {
        const int i = i0 + is * 16 + l15;
        #pragma unroll
        for (int ct = 0; ct < 4; ++ct) {
            #pragma unroll
            for (int r = 0; r < 4; ++r) {
                const int c = w * 64 + ct * 16 + quad * 4 + r;
                const size_t idx = ((size_t)(b * C_ + c)) * N_ + i;
                out[idx] = g * (acc[ct][is][r] * linv[is]) + x[idx];
            }
        }
    }
}

// ---------------------------------------------------------------------------
extern "C" void kernel_launch(void* const* d_in, const int* in_sizes, int n_in,
                              void* d_out, int out_size, void* d_ws, size_t ws_size,
                              hipStream_t stream)
{
    const float* x     = (const float*)d_in[0];
    const float* Wq    = (const float*)d_in[1];
    const float* bq    = (const float*)d_in[2];
    const float* Wk    = (const float*)d_in[3];
    const float* bk    = (const float*)d_in[4];
    const float* Wv    = (const float*)d_in[5];
    const float* bv    = (const float*)d_in[6];
    const float* gamma = (const float*)d_in[7];
    float* out = (float*)d_out;

    char* ws = (char*)d_ws;
    f16* qt  = (f16*)ws;                                   // B*N*M   ( 2 MB)
    f16* ktf = qt + (size_t)B_ * N_ * M_;                  // B*N*M   ( 2 MB)
    f16* vf  = ktf + (size_t)B_ * N_ * M_;                 // B*C*N   (16 MB)
    f16* Wf  = vf + (size_t)B_ * C_ * N_;                  // 640*512 (0.6 MB)

    wcvt<<<dim3(160), 256, 0, stream>>>(Wq, Wk, Wv, Wf);
    qkv2<<<dim3(N_ / 64, B_), 512, 0, stream>>>(Wf, x, bq, bk, bv, qt, ktf, vf);
    attn<<<dim3(256), 512, 0, stream>>>(qt, ktf, vf, x, gamma, out);
}